// Round 5
// baseline (571.140 us; speedup 1.0000x reference)
//
#include <hip/hip_runtime.h>

// GaussianSoftmax: out[b,n,m] = softmax_m( exp( exp(-max(||x_n-x_m||^2,0)/sigma) ) )
// X: [8, 4096, 16] fp32, sigma: [1], out: [8, 4096, 4096] fp32 (512 MiB).
//
// R16 = R15 with ONE change: regular stores instead of nontemporal.
// Evidence: R13 (heavy VALU, nt) gs ~205us; R14 (MFMA, scattered nt) ~250us;
// R15 (MFMA, contiguous nt) ~200us -> all pinned at 512MiB/~200us = 2.56 TB/s
// by the store path, while the harness fill kernel writes the SAME buffer at
// 6.26 TB/s with regular (cached) stores. Theory: gfx950 nt stores bypass
// L2 write-combining and plateau ~2.5 TB/s; cached writes stream at ~6.3.
// Everything else byte-identical to R15 (harness-verified, absmax 1.9e-6).

typedef float v4f __attribute__((ext_vector_type(4)));
typedef short bf8 __attribute__((ext_vector_type(8)));

constexpr int Bn  = 8;
constexpr int N   = 4096;
constexpr int F   = 16;
constexpr int BM  = 16;            // softmax rows per block (= MFMA tile n)
constexpr int BLK = 1024;          // 16 waves
constexpr int NW  = BLK / 64;      // 16
constexpr int TPW = (N / 16) / NW; // 16 m-tiles per wave

__device__ __forceinline__ unsigned short f2bf(float x) {   // RNE
    unsigned int u = __float_as_uint(x);
    unsigned int r = (u + 0x7FFFu + ((u >> 16) & 1u)) >> 16;
    return (unsigned short)r;
}
__device__ __forceinline__ float bf2f(unsigned short h) {
    return __uint_as_float(((unsigned int)h) << 16);
}
__device__ __forceinline__ float uni(float x) {
    return __int_as_float(__builtin_amdgcn_readfirstlane(__float_as_int(x)));
}

__global__ __launch_bounds__(256)
void pack_kernel(const float* __restrict__ X, uint4* __restrict__ Xp,
                 float* __restrict__ sqm) {
    const int b = blockIdx.y;
    const int m = blockIdx.x * 256 + threadIdx.x;
    const float4* src = (const float4*)(X + ((size_t)b * N + m) * F);
    const float4 v0 = src[0], v1 = src[1], v2 = src[2], v3 = src[3];
    const float x[F] = {v0.x, v0.y, v0.z, v0.w, v1.x, v1.y, v1.z, v1.w,
                        v2.x, v2.y, v2.z, v2.w, v3.x, v3.y, v3.z, v3.w};
    float s = 0.f;
    #pragma unroll
    for (int f = 0; f < F; ++f) s = fmaf(x[f], x[f], s);
    sqm[(size_t)b * N + m] = s;

    uint4* dst = Xp + ((size_t)b * N + m) * 4;
    #pragma unroll
    for (int g = 0; g < 4; ++g) {
        unsigned int hi[4], lo[4];
        #pragma unroll
        for (int j = 0; j < 4; ++j) {
            const float xf = x[4 * g + j];
            const unsigned short h = f2bf(xf);
            hi[j] = h;
            lo[j] = f2bf(xf - bf2f(h));
        }
        uint4 c;
        c.x = hi[0] | (hi[1] << 16);
        c.y = hi[2] | (hi[3] << 16);
        c.z = lo[0] | (lo[1] << 16);
        c.w = lo[2] | (lo[3] << 16);
        dst[g] = c;
    }
}

union BfU { uint4 u; bf8 h; };

__global__ __launch_bounds__(BLK)
void gs_mfma(const uint4* __restrict__ Xp, const float* __restrict__ sqm,
             const float* __restrict__ sigma_p, float* __restrict__ out) {
    extern __shared__ char smem[];
    unsigned short (*lds_e)[N] = (unsigned short (*)[N])smem;       // 128 KiB
    float* red = (float*)(smem + (size_t)BM * N * 2);               // NW x BM

    const int tid  = threadIdx.x;
    const int w    = tid >> 6;
    const int lane = tid & 63;
    const int g    = lane >> 4;
    const int c    = lane & 15;
    const int b    = blockIdx.y;
    const int n0   = blockIdx.x * BM;

    const uint4* Xpb = Xp + (size_t)b * N * 4;
    const float* sqb = sqm + (size_t)b * N;

    // Block-constant B frags (n-side rows n0..n0+15), hi/lo and swapped.
    BfU b1; b1.u = Xpb[(size_t)(n0 + c) * 4 + g];
    BfU b2; b2.u = make_uint4(b1.u.z, b1.u.w, b1.u.x, b1.u.y);

    const float sqn_l = sqb[n0 + c];
    const float nis   = uni(-1.0f / sigma_p[0]);

    float psum = 0.f;

    #pragma unroll
    for (int t = 0; t < TPW; ++t) {
        const int m_tile = w * (TPW * 16) + t * 16;
        BfU a; a.u = Xpb[(size_t)(m_tile + c) * 4 + g];

        v4f acc = {0.f, 0.f, 0.f, 0.f};
        acc = __builtin_amdgcn_mfma_f32_16x16x32_bf16(a.h, b1.h, acc, 0, 0, 0);
        acc = __builtin_amdgcn_mfma_f32_16x16x32_bf16(a.h, b2.h, acc, 0, 0, 0);
        // acc[j] = inner(x_{m_tile+4g+j}, x_{n0+c})

        const v4f sm4 = *(const v4f*)(sqb + m_tile + 4 * g);
        float ex = __expf(__expf(fmaxf(fmaf(-2.f, acc.x, sqn_l + sm4.x), 0.f) * nis));
        float ey = __expf(__expf(fmaxf(fmaf(-2.f, acc.y, sqn_l + sm4.y), 0.f) * nis));
        float ez = __expf(__expf(fmaxf(fmaf(-2.f, acc.z, sqn_l + sm4.z), 0.f) * nis));
        float ew = __expf(__expf(fmaxf(fmaf(-2.f, acc.w, sqn_l + sm4.w), 0.f) * nis));

        ushort4 pk;
        pk.x = f2bf(ex); pk.y = f2bf(ey); pk.z = f2bf(ez); pk.w = f2bf(ew);
        // logical 4-elem granule -> physical via row-XOR swizzle (bits 2-5)
        const int gl = (m_tile >> 2) + g;
        const int gp = gl ^ (c << 2);
        *(ushort4*)&lds_e[c][4 * gp] = pk;    // b64, banks uniformly spread

        psum += (ex + ey) + (ez + ew);
    }

    // Row-sum for row n0+c: fold the 4 g-groups, then the 16 waves.
    psum += __shfl_xor(psum, 16, 64);
    psum += __shfl_xor(psum, 32, 64);
    if (lane < 16) red[w * BM + lane] = psum;
    __syncthreads();   // lds_e + red visible

    // Wave w handles softmax row w: total = sum over waves' partials.
    float tot = 0.f;
    #pragma unroll
    for (int w2 = 0; w2 < NW; ++w2) tot += red[w2 * BM + w];   // broadcast
    const float inv = uni(1.0f / tot);

    // Store row w: contiguous LDS read (conflict-free), XOR gives an
    // in-window lane permutation on the global address -> each instruction
    // covers one contiguous 1 KiB segment of the row (full 128B lines).
    // REGULAR stores (not nt): stream through L2 write-combining at full BW.
    float* rowp = out + ((size_t)b * N + n0 + w) * (size_t)N;
    #pragma unroll
    for (int k = 0; k < N / 4 / 64; ++k) {     // 16 iterations
        const int gp = 64 * k + lane;
        const int gl = gp ^ (w << 2);
        const ushort4 pk = *(const ushort4*)&lds_e[w][4 * gp];
        v4f v;
        v.x = bf2f(pk.x) * inv;
        v.y = bf2f(pk.y) * inv;
        v.z = bf2f(pk.z) * inv;
        v.w = bf2f(pk.w) * inv;
        ((v4f*)rowp)[gl] = v;
    }
}

extern "C" void kernel_launch(void* const* d_in, const int* in_sizes, int n_in,
                              void* d_out, int out_size, void* d_ws, size_t ws_size,
                              hipStream_t stream) {
    const float* X     = (const float*)d_in[0];
    const float* sigma = (const float*)d_in[1];
    float* out         = (float*)d_out;
    uint4* Xp          = (uint4*)d_ws;                              // 2 MiB
    float* sqm         = (float*)d_ws + (size_t)Bn * N * 16;        // +128 KiB

    const size_t lds_bytes = (size_t)BM * N * 2 + NW * BM * 4;      // 129 KiB
    pack_kernel<<<dim3(N / 256, Bn), 256, 0, stream>>>(X, Xp, sqm);
    gs_mfma<<<dim3(N / BM, Bn), BLK, lds_bytes, stream>>>(Xp, sqm, sigma, out);
}

// Round 6
// 558.132 us; speedup vs baseline: 1.0233x; 1.0233x over previous
//
#include <hip/hip_runtime.h>

// GaussianSoftmax: out[b,n,m] = softmax_m( exp( exp(-max(||x_n-x_m||^2,0)/sigma) ) )
// X: [8, 4096, 16] fp32, sigma: [1], out: [8, 4096, 4096] fp32 (512 MiB).
//
// R17 = R15 with ONE change: LDS row PAD (stride 8200 B) instead of XOR
// granule swizzle. R15's XOR permuted the lane->global-address mapping in the
// store loop (16B granules shuffled inside each 1 KiB window); if the
// coalescer is order-sensitive that fragments wave-stores into sub-line
// transactions, masking the MFMA compute win (R13 ~= R15 observed). With the
// pad, the store loop is byte-identical in address pattern to R13's proven
// monotone contiguous 1 KiB/instruction stores; LDS write conflicts only
// 4-way (bank = 2(c+g) mod 32, ~0.6us/block), read side contiguous-optimal.
// nt stores kept (R15 555.6 < R16 571.1 measured).
// e in (1,2.72] bf16 RNE -> out err <=1.3e-6 (harness-verified 1.9e-6).

typedef float v4f __attribute__((ext_vector_type(4)));
typedef short bf8 __attribute__((ext_vector_type(8)));

constexpr int Bn  = 8;
constexpr int N   = 4096;
constexpr int F   = 16;
constexpr int BM  = 16;            // softmax rows per block (= MFMA tile n)
constexpr int BLK = 1024;          // 16 waves
constexpr int NW  = BLK / 64;      // 16
constexpr int TPW = (N / 16) / NW; // 16 m-tiles per wave
constexpr int ROWB = N * 2 + 8;    // 8200 B padded LDS row stride

__device__ __forceinline__ unsigned short f2bf(float x) {   // RNE
    unsigned int u = __float_as_uint(x);
    unsigned int r = (u + 0x7FFFu + ((u >> 16) & 1u)) >> 16;
    return (unsigned short)r;
}
__device__ __forceinline__ float bf2f(unsigned short h) {
    return __uint_as_float(((unsigned int)h) << 16);
}
__device__ __forceinline__ float uni(float x) {
    return __int_as_float(__builtin_amdgcn_readfirstlane(__float_as_int(x)));
}

__global__ __launch_bounds__(256)
void pack_kernel(const float* __restrict__ X, uint4* __restrict__ Xp,
                 float* __restrict__ sqm) {
    const int b = blockIdx.y;
    const int m = blockIdx.x * 256 + threadIdx.x;
    const float4* src = (const float4*)(X + ((size_t)b * N + m) * F);
    const float4 v0 = src[0], v1 = src[1], v2 = src[2], v3 = src[3];
    const float x[F] = {v0.x, v0.y, v0.z, v0.w, v1.x, v1.y, v1.z, v1.w,
                        v2.x, v2.y, v2.z, v2.w, v3.x, v3.y, v3.z, v3.w};
    float s = 0.f;
    #pragma unroll
    for (int f = 0; f < F; ++f) s = fmaf(x[f], x[f], s);
    sqm[(size_t)b * N + m] = s;

    uint4* dst = Xp + ((size_t)b * N + m) * 4;
    #pragma unroll
    for (int g = 0; g < 4; ++g) {
        unsigned int hi[4], lo[4];
        #pragma unroll
        for (int j = 0; j < 4; ++j) {
            const float xf = x[4 * g + j];
            const unsigned short h = f2bf(xf);
            hi[j] = h;
            lo[j] = f2bf(xf - bf2f(h));
        }
        uint4 c;
        c.x = hi[0] | (hi[1] << 16);
        c.y = hi[2] | (hi[3] << 16);
        c.z = lo[0] | (lo[1] << 16);
        c.w = lo[2] | (lo[3] << 16);
        dst[g] = c;
    }
}

union BfU { uint4 u; bf8 h; };

__global__ __launch_bounds__(BLK)
void gs_mfma(const uint4* __restrict__ Xp, const float* __restrict__ sqm,
             const float* __restrict__ sigma_p, float* __restrict__ out) {
    extern __shared__ char smem[];
    // lds_e: BM rows x (N bf16 + 8B pad) = 16 x 8200 B
    float* red = (float*)(smem + (size_t)BM * ROWB);                // NW x BM

    const int tid  = threadIdx.x;
    const int w    = tid >> 6;
    const int lane = tid & 63;
    const int g    = lane >> 4;
    const int c    = lane & 15;
    const int b    = blockIdx.y;
    const int n0   = blockIdx.x * BM;

    const uint4* Xpb = Xp + (size_t)b * N * 4;
    const float* sqb = sqm + (size_t)b * N;

    // Block-constant B frags (n-side rows n0..n0+15), hi/lo and swapped.
    BfU b1; b1.u = Xpb[(size_t)(n0 + c) * 4 + g];
    BfU b2; b2.u = make_uint4(b1.u.z, b1.u.w, b1.u.x, b1.u.y);

    const float sqn_l = sqb[n0 + c];
    const float nis   = uni(-1.0f / sigma_p[0]);

    float psum = 0.f;

    #pragma unroll
    for (int t = 0; t < TPW; ++t) {
        const int m_tile = w * (TPW * 16) + t * 16;
        BfU a; a.u = Xpb[(size_t)(m_tile + c) * 4 + g];

        v4f acc = {0.f, 0.f, 0.f, 0.f};
        acc = __builtin_amdgcn_mfma_f32_16x16x32_bf16(a.h, b1.h, acc, 0, 0, 0);
        acc = __builtin_amdgcn_mfma_f32_16x16x32_bf16(a.h, b2.h, acc, 0, 0, 0);
        // acc[j] = inner(x_{m_tile+4g+j}, x_{n0+c})

        const v4f sm4 = *(const v4f*)(sqb + m_tile + 4 * g);
        float ex = __expf(__expf(fmaxf(fmaf(-2.f, acc.x, sqn_l + sm4.x), 0.f) * nis));
        float ey = __expf(__expf(fmaxf(fmaf(-2.f, acc.y, sqn_l + sm4.y), 0.f) * nis));
        float ez = __expf(__expf(fmaxf(fmaf(-2.f, acc.z, sqn_l + sm4.z), 0.f) * nis));
        float ew = __expf(__expf(fmaxf(fmaf(-2.f, acc.w, sqn_l + sm4.w), 0.f) * nis));

        ushort4 pk;
        pk.x = f2bf(ex); pk.y = f2bf(ey); pk.z = f2bf(ez); pk.w = f2bf(ew);
        // row c, 8B granule gl; padded stride -> banks 2(c+g) mod 32 (4-way max)
        const int gl = (m_tile >> 2) + g;              // w*64 + t*4 + g
        *(ushort4*)(smem + (size_t)c * ROWB + 8 * gl) = pk;

        psum += (ex + ey) + (ez + ew);
    }

    // Row-sum for row n0+c: fold the 4 g-groups, then the 16 waves.
    psum += __shfl_xor(psum, 16, 64);
    psum += __shfl_xor(psum, 32, 64);
    if (lane < 16) red[w * BM + lane] = psum;
    __syncthreads();   // lds_e + red visible

    // Wave w handles softmax row w: total = sum over waves' partials.
    float tot = 0.f;
    #pragma unroll
    for (int w2 = 0; w2 < NW; ++w2) tot += red[w2 * BM + w];   // broadcast
    const float inv = uni(1.0f / tot);

    // Store row w: contiguous LDS read, MONOTONE contiguous global stores
    // (1 KiB per wave-instruction, identical pattern to R13's proven store).
    float* rowp = out + ((size_t)b * N + n0 + w) * (size_t)N;
    #pragma unroll
    for (int k = 0; k < N / 4 / 64; ++k) {     // 16 iterations
        const int gp = 64 * k + lane;
        const ushort4 pk = *(const ushort4*)(smem + (size_t)w * ROWB + 8 * gp);
        v4f v;
        v.x = bf2f(pk.x) * inv;
        v.y = bf2f(pk.y) * inv;
        v.z = bf2f(pk.z) * inv;
        v.w = bf2f(pk.w) * inv;
        __builtin_nontemporal_store(v, (v4f*)rowp + gp);
    }
}

extern "C" void kernel_launch(void* const* d_in, const int* in_sizes, int n_in,
                              void* d_out, int out_size, void* d_ws, size_t ws_size,
                              hipStream_t stream) {
    const float* X     = (const float*)d_in[0];
    const float* sigma = (const float*)d_in[1];
    float* out         = (float*)d_out;
    uint4* Xp          = (uint4*)d_ws;                              // 2 MiB
    float* sqm         = (float*)d_ws + (size_t)Bn * N * 16;        // +128 KiB

    const size_t lds_bytes = (size_t)BM * ROWB + NW * BM * 4;       // ~129.2 KiB
    pack_kernel<<<dim3(N / 256, Bn), 256, 0, stream>>>(X, Xp, sqm);
    gs_mfma<<<dim3(N / BM, Bn), BLK, lds_bytes, stream>>>(Xp, sqm, sigma, out);
}